// Round 8
// baseline (224.025 us; speedup 1.0000x reference)
//
#include <hip/hip_runtime.h>
#include <stdint.h>

#define D_  1024
#define S_  2048
#define B_  2
#define H_  16
#define HD_ 64
#define M_  (B_*S_)   // 4096
#define KVB 64

typedef unsigned short u16;
typedef __attribute__((ext_vector_type(8)))  __bf16 bf16x8;
typedef __attribute__((ext_vector_type(4)))  float  f32x4;
typedef __attribute__((ext_vector_type(16))) float  f32x16;

__device__ __forceinline__ u16 f2bf(float f) {
    __bf16 h = (__bf16)f;
    union { __bf16 h; u16 u; } x; x.h = h;
    return x.u;
}

__device__ __forceinline__ void gload_lds16(const void* g, void* l) {
    __builtin_amdgcn_global_load_lds(
        (const __attribute__((address_space(1))) uint32_t*)g,
        (__attribute__((address_space(3))) uint32_t*)l, 16, 0, 0);
}

// ---------------- prep: fp32->bf16 cvt (x3) + W transpose (x3), one launch --
__global__ __launch_bounds__(256) void prep_kernel(
    const float* __restrict__ q, const float* __restrict__ k, const float* __restrict__ v,
    u16* __restrict__ Xq, u16* __restrict__ Xk, u16* __restrict__ Xv,
    const float* __restrict__ Wq, const float* __restrict__ Wk, const float* __restrict__ Wv,
    u16* __restrict__ Wtq, u16* __restrict__ Wtk, u16* __restrict__ Wtv)
{
    __shared__ u16 t[64][65];
    int bid = blockIdx.x;
    if (bid < 12288) {                       // cvt: 3 x 4096 blocks
        int sl = bid >> 12;
        int bx = bid & 4095;
        const float* in = sl == 0 ? q : (sl == 1 ? k : v);
        u16* out = sl == 0 ? Xq : (sl == 1 ? Xk : Xv);
        int i = (bx * 256 + threadIdx.x) * 4;
        float4 vv = *(const float4*)(in + i);
        ushort4 o;
        o.x = f2bf(vv.x); o.y = f2bf(vv.y); o.z = f2bf(vv.z); o.w = f2bf(vv.w);
        *(ushort4*)(out + i) = o;
    } else {                                 // transpose: 3 x 256 blocks
        int tt = bid - 12288;
        int z = tt >> 8;
        int rem = tt & 255;
        const float* W = z == 0 ? Wq : (z == 1 ? Wk : Wv);
        u16* Wt = z == 0 ? Wtq : (z == 1 ? Wtk : Wtv);
        int k0 = (rem & 15) * 64, n0 = (rem >> 4) * 64;
        int tid = threadIdx.x;
        int c4 = (tid & 15) * 4, r = tid >> 4;
#pragma unroll
        for (int i = 0; i < 4; i++) {
            int row = r + i * 16;
            float4 vv = *(const float4*)(W + (uint64_t)(k0 + row) * D_ + n0 + c4);
            t[row][c4 + 0] = f2bf(vv.x);
            t[row][c4 + 1] = f2bf(vv.y);
            t[row][c4 + 2] = f2bf(vv.z);
            t[row][c4 + 3] = f2bf(vv.w);
        }
        __syncthreads();
#pragma unroll
        for (int i = 0; i < 4; i++) {
            int nrow = r + i * 16;
            ushort4 o;
            o.x = t[c4 + 0][nrow]; o.y = t[c4 + 1][nrow];
            o.z = t[c4 + 2][nrow]; o.w = t[c4 + 3][nrow];
            *(ushort4*)(Wt + (uint64_t)(n0 + nrow) * D_ + k0 + c4) = o;
        }
    }
}

// ---------------- QKV projection GEMM: 64x128 tile, BK=32 ------------------
// 4 waves, each wave a 32x64 quadrant -> acc[2][4] = 32 AGPR.
// Depth-2 pipeline: 3 LDS buffers, raw s_barrier + counted vmcnt(3).
// LDS chunk-swizzle (c ^= (row>>1)&3) keeps ds_read_b128 conflict-free.
__global__ __launch_bounds__(256) void gemm_qkv(
    const u16* __restrict__ Xq, const u16* __restrict__ Xk, const u16* __restrict__ Xv,
    const u16* __restrict__ Wtq, const u16* __restrict__ Wtk, const u16* __restrict__ Wtv,
    const float* __restrict__ bq, const float* __restrict__ bk, const float* __restrict__ bv,
    u16* __restrict__ Qo, u16* __restrict__ Ko, u16* __restrict__ Vo)
{
    int p = blockIdx.z;
    const u16* X    = p == 0 ? Xq  : (p == 1 ? Xk  : Xv);
    const u16* Wt   = p == 0 ? Wtq : (p == 1 ? Wtk : Wtv);
    const float* bias = p == 0 ? bq : (p == 1 ? bk : bv);
    u16* out = p == 0 ? Qo : (p == 1 ? Ko : Vo);
    // Q: fold 1/sqrt(HD) AND log2(e) -> softmax runs in exp2 domain
    float scale = p == 0 ? 0.18033688f : 1.0f;

    __shared__ __align__(16) u16 As[3][64 * 32];    // 12 KB
    __shared__ __align__(16) u16 Bs[3][128 * 32];   // 24 KB

    int tid = threadIdx.x;
    int lane = tid & 63, wid = tid >> 6;
    int lrow = lane & 15, lk = lane >> 4;
    int wr = wid >> 1, wc = wid & 1;
    int bm = blockIdx.x, bn = blockIdx.y;

    f32x4 acc[2][4] = {};

    const uint64_t Xrow0 = (uint64_t)bm * 64 * D_;
    const uint64_t Wrow0 = (uint64_t)bn * 128 * D_;

    auto stage = [&](int buf, int kt) {
        int k0 = kt * 32;
        {
            int row = tid >> 2;
            int cg = (tid & 3) ^ ((row >> 1) & 3);
            gload_lds16(X + Xrow0 + (uint64_t)row * D_ + k0 + cg * 8,
                        (char*)As[buf] + wid * 1024);
        }
#pragma unroll
        for (int it = 0; it < 2; ++it) {
            int i = it * 256 + tid;
            int row = i >> 2;
            int cg = (i & 3) ^ ((row >> 1) & 3);
            gload_lds16(Wt + Wrow0 + (uint64_t)row * D_ + k0 + cg * 8,
                        (char*)Bs[buf] + it * 4096 + wid * 1024);
        }
    };

    stage(0, 0);
    stage(1, 1);
    asm volatile("s_waitcnt vmcnt(3)" ::: "memory");
    __builtin_amdgcn_s_barrier();

    const int NKT = D_ / 32;   // 32
    for (int kt = 0; kt < NKT; ++kt) {
        int cur = kt % 3;
        if (kt + 2 < NKT) stage((kt + 2) % 3, kt + 2);

        bf16x8 a[2], b[4];
#pragma unroll
        for (int m = 0; m < 2; m++) {
            int r = wr * 32 + m * 16 + lrow;
            a[m] = *(const bf16x8*)((const char*)As[cur] + r * 64 + ((lk ^ ((r >> 1) & 3)) * 16));
        }
#pragma unroll
        for (int n = 0; n < 4; n++) {
            int r = wc * 64 + n * 16 + lrow;
            b[n] = *(const bf16x8*)((const char*)Bs[cur] + r * 64 + ((lk ^ ((r >> 1) & 3)) * 16));
        }
        if (p < 2) {
#pragma unroll
            for (int m = 0; m < 2; m++)
#pragma unroll
                for (int n = 0; n < 4; n++)
                    acc[m][n] = __builtin_amdgcn_mfma_f32_16x16x32_bf16(a[m], b[n], acc[m][n], 0, 0, 0);
        } else {  // V: compute C^T so VT stores coalesce
#pragma unroll
            for (int m = 0; m < 2; m++)
#pragma unroll
                for (int n = 0; n < 4; n++)
                    acc[m][n] = __builtin_amdgcn_mfma_f32_16x16x32_bf16(b[n], a[m], acc[m][n], 0, 0, 0);
        }

        if (kt + 1 < NKT) {
            if (kt + 2 < NKT)
                asm volatile("s_waitcnt vmcnt(3)" ::: "memory");
            else
                asm volatile("s_waitcnt vmcnt(0)" ::: "memory");
            __builtin_amdgcn_s_barrier();
        }
    }

    if (p < 2) {
#pragma unroll
        for (int m = 0; m < 2; m++) {
            int grow_base = bm * 64 + wr * 32 + m * 16 + lk * 4;
#pragma unroll
            for (int n = 0; n < 4; n++) {
                int gcol = bn * 128 + wc * 64 + n * 16 + lrow;
                float bb = bias[gcol];
                int h = gcol >> 6, hd = gcol & 63;
#pragma unroll
                for (int j = 0; j < 4; j++) {
                    int grow = grow_base + j;
                    int b_ = grow >> 11, s = grow & 2047;
                    out[(((uint64_t)(b_ * H_ + h)) * S_ + s) * HD_ + hd] =
                        f2bf((acc[m][n][j] + bb) * scale);
                }
            }
        }
    } else {
#pragma unroll
        for (int m = 0; m < 2; m++) {
            int sg = bm * 64 + wr * 32 + m * 16 + lrow;
            int b_ = sg >> 11, s = sg & 2047;
#pragma unroll
            for (int n = 0; n < 4; n++) {
                int ch_base = bn * 128 + wc * 64 + n * 16 + lk * 4;
#pragma unroll
                for (int j = 0; j < 4; j++) {
                    int ch = ch_base + j;
                    int h = ch >> 6, hd = ch & 63;
                    out[(((uint64_t)(b_ * H_ + h)) * HD_ + hd) * S_ + s] =
                        f2bf(acc[m][n][j] + bias[ch]);
                }
            }
        }
    }
}

// ---------------- flash attention: 8 waves x 32 q-rows (QBLK=256), KVBLK=64 -
// Swapped QK^T (mfma(K,Q)): lane holds P-row slice for q=lane&31 -> in-reg
// softmax in exp2 domain (log2e folded into Q): tree max (ILP), defer-max
// rescale skip (T13, THR=8), tree sum, cvt_pk+permlane32 P redistribution
// (T12). PV swapped (mfma(VT,P) -> D[hd][q]) so m/l stay lane-aligned.
__global__ __launch_bounds__(512) void attn_kernel(
    const u16* __restrict__ Q, const u16* __restrict__ K,
    const u16* __restrict__ VT, float* __restrict__ out)
{
    __shared__ __align__(16) char smem[32768];  // K dbuf 16K | V dbuf 16K; scr overlays

    int lin = blockIdx.x;
    int bh = lin & 31, qt = lin >> 5;

    int tid = threadIdx.x;
    int w = tid >> 6, lane = tid & 63;
    int q5 = lane & 31, h = lane >> 5;

    bf16x8 qf[4];
    const u16* Qrow = Q + ((uint64_t)bh * S_ + qt * 256 + w * 32 + q5) * HD_;
#pragma unroll
    for (int kk = 0; kk < 4; kk++)
        qf[kk] = *(const bf16x8*)(Qrow + kk * 16 + h * 8);

    f32x16 o_acc[2] = {};
    float m_run = -1e30f, l_run = 0.f;

    const char* Kbase = (const char*)(K  + (uint64_t)bh * S_ * HD_);
    const char* Vbase = (const char*)(VT + (uint64_t)bh * HD_ * S_);

    int o16 = tid * 16;
    int rr  = o16 >> 7;
    int os  = o16 ^ ((rr & 7) << 4);

    auto stage = [&](int buf, int t) {
        int kv0 = t * KVB;
        gload_lds16(Kbase + (uint64_t)kv0 * 128 + os,
                    smem + buf * 8192 + w * 1024);
        gload_lds16(Vbase + (uint64_t)rr * (S_ * 2) + kv0 * 2 + (os & 127),
                    smem + 16384 + buf * 8192 + w * 1024);
    };

    stage(0, 0);
    __syncthreads();
    int cur = 0;

    const int NT = S_ / KVB;
    for (int t = 0; t < NT; ++t) {
        if (t + 1 < NT) stage(cur ^ 1, t + 1);

        const char* Kc = smem + cur * 8192;
        const char* Vc = smem + 16384 + cur * 8192;
        int sw = (q5 & 7) << 4;

        // ---- S^T = K Q^T (scores already in log2 units) ----
        f32x16 sacc[2] = {};
        __builtin_amdgcn_s_setprio(1);
#pragma unroll
        for (int c = 0; c < 2; c++) {
            int rb = (c * 32 + q5) * 128;
#pragma unroll
            for (int kk = 0; kk < 4; kk++) {
                bf16x8 kf = *(const bf16x8*)(Kc + rb + ((kk * 32 + h * 16) ^ sw));
                sacc[c] = __builtin_amdgcn_mfma_f32_32x32x16_bf16(kf, qf[kk], sacc[c], 0, 0, 0);
            }
        }
        __builtin_amdgcn_s_setprio(0);

        // ---- row max: depth-5 tree (ILP) + cross-half swap ----
        float tm[16];
#pragma unroll
        for (int r = 0; r < 16; r++) tm[r] = fmaxf(sacc[0][r], sacc[1][r]);
#pragma unroll
        for (int s2 = 8; s2 > 0; s2 >>= 1)
#pragma unroll
            for (int r = 0; r < s2; r++) tm[r] = fmaxf(tm[r], tm[r + s2]);
        float pmax = fmaxf(tm[0], __shfl_xor(tm[0], 32, 64));

        // ---- defer-max (T13): skip O/l rescale while growth <= 8 (P<=256) --
        if (!__all(pmax - m_run <= 8.0f)) {
            float mnew = fmaxf(m_run, pmax);
            float sc = __builtin_exp2f(m_run - mnew);
            m_run = mnew;
            l_run *= sc;
#pragma unroll
            for (int hb = 0; hb < 2; hb++)
#pragma unroll
                for (int r = 0; r < 16; r++) o_acc[hb][r] *= sc;
        }

        // ---- P = exp2(s - m), 4-way parallel sum accumulators ----
        float ts0 = 0.f, ts1 = 0.f, ts2 = 0.f, ts3 = 0.f;
#pragma unroll
        for (int c = 0; c < 2; c++)
#pragma unroll
            for (int r = 0; r < 16; r += 4) {
                float p0 = __builtin_exp2f(sacc[c][r + 0] - m_run);
                float p1 = __builtin_exp2f(sacc[c][r + 1] - m_run);
                float p2 = __builtin_exp2f(sacc[c][r + 2] - m_run);
                float p3 = __builtin_exp2f(sacc[c][r + 3] - m_run);
                sacc[c][r + 0] = p0; sacc[c][r + 1] = p1;
                sacc[c][r + 2] = p2; sacc[c][r + 3] = p3;
                ts0 += p0; ts1 += p1; ts2 += p2; ts3 += p3;
            }
        float ts = (ts0 + ts1) + (ts2 + ts3);
        ts += __shfl_xor(ts, 32, 64);
        l_run += ts;

        // ---- P -> PV B-operand: cvt_pk pairs + permlane32_swap (T12) ----
        bf16x8 pa[4];
#pragma unroll
        for (int ks = 0; ks < 4; ks++) {
            int c = ks >> 1, gg = ks & 1;
            uint32_t a0, a1, b0, b1;
            asm("v_cvt_pk_bf16_f32 %0, %1, %2" : "=v"(a0) : "v"(sacc[c][8*gg+0]), "v"(sacc[c][8*gg+1]));
            asm("v_cvt_pk_bf16_f32 %0, %1, %2" : "=v"(a1) : "v"(sacc[c][8*gg+2]), "v"(sacc[c][8*gg+3]));
            asm("v_cvt_pk_bf16_f32 %0, %1, %2" : "=v"(b0) : "v"(sacc[c][8*gg+4]), "v"(sacc[c][8*gg+5]));
            asm("v_cvt_pk_bf16_f32 %0, %1, %2" : "=v"(b1) : "v"(sacc[c][8*gg+6]), "v"(sacc[c][8*gg+7]));
            asm volatile("v_permlane32_swap_b32 %0, %1" : "+v"(a0), "+v"(b0));
            asm volatile("v_permlane32_swap_b32 %0, %1" : "+v"(a1), "+v"(b1));
            union { uint32_t u[4]; bf16x8 v; } pu;
            pu.u[0] = a0; pu.u[1] = a1; pu.u[2] = b0; pu.u[3] = b1;
            pa[ks] = pu.v;
        }

        // ---- O^T += V^T P^T ----
        __builtin_amdgcn_s_setprio(1);
#pragma unroll
        for (int hb = 0; hb < 2; hb++) {
            int rb = (hb * 32 + q5) * 128;
#pragma unroll
            for (int ks = 0; ks < 4; ks++) {
                bf16x8 vf = *(const bf16x8*)(Vc + rb + ((ks * 32 + h * 16) ^ sw));
                o_acc[hb] = __builtin_amdgcn_mfma_f32_32x32x16_bf16(vf, pa[ks], o_acc[hb], 0, 0, 0);
            }
        }
        __builtin_amdgcn_s_setprio(0);

        __syncthreads();
        cur ^= 1;
    }

    // ---- epilogue: per-wave 32x32 f32 LDS transpose (overlays K/V bufs) ----
    float inv = 1.0f / l_run;
    int b_ = bh >> 4, head = bh & 15;
    int qq = lane >> 1, c0 = (lane & 1) * 16;
    float* scrw = (float*)smem + w * 1024;
    float* orow = out + ((uint64_t)(b_ * S_ + qt * 256 + w * 32 + qq)) * D_ + head * 64;
#pragma unroll
    for (int hb = 0; hb < 2; hb++) {
#pragma unroll
        for (int r = 0; r < 16; r++) {
            int col = (r & 3) + 8 * (r >> 2) + 4 * h;
            scrw[q5 * 32 + (col ^ ((q5 & 7) << 2))] = o_acc[hb][r] * inv;
        }
        __syncthreads();
#pragma unroll
        for (int j = 0; j < 4; j++) {
            int cb = c0 + j * 4;
            float4 val = *(float4*)&scrw[qq * 32 + (cb ^ ((qq & 7) << 2))];
            *(float4*)(orow + hb * 32 + cb) = val;
        }
        __syncthreads();
    }
}

// ---------------- launcher ----------------
extern "C" void kernel_launch(void* const* d_in, const int* in_sizes, int n_in,
                              void* d_out, int out_size, void* d_ws, size_t ws_size,
                              hipStream_t stream) {
    const float* q  = (const float*)d_in[0];
    const float* k  = (const float*)d_in[1];
    const float* v  = (const float*)d_in[2];
    const float* Wq = (const float*)d_in[3];
    const float* bq = (const float*)d_in[4];
    const float* Wk = (const float*)d_in[5];
    const float* bk = (const float*)d_in[6];
    const float* Wv = (const float*)d_in[7];
    const float* bv = (const float*)d_in[8];
    float* out = (float*)d_out;

    u16* ws = (u16*)d_ws;
    const size_t XN = (size_t)M_ * D_;   // 4 Mi elems
    const size_t WN = (size_t)D_ * D_;   // 1 Mi elems
    u16* Xq  = ws;          u16* Xk  = Xq  + XN;  u16* Xv  = Xk  + XN;
    u16* Wtq = Xv + XN;     u16* Wtk = Wtq + WN;  u16* Wtv = Wtk + WN;
    u16* Qb  = Wtv + WN;    u16* Kb  = Qb  + XN;  u16* Vb  = Kb  + XN;

    prep_kernel<<<13056, 256, 0, stream>>>(q, k, v, Xq, Xk, Xv,
                                           Wq, Wk, Wv, Wtq, Wtk, Wtv);
    gemm_qkv<<<dim3(64, 8, 3), 256, 0, stream>>>(Xq, Xk, Xv, Wtq, Wtk, Wtv,
                                                 bq, bk, bv, Qb, Kb, Vb);
    attn_kernel<<<256, 512, 0, stream>>>(Qb, Kb, Vb, out);
}

// Round 9
// 212.330 us; speedup vs baseline: 1.0551x; 1.0551x over previous
//
#include <hip/hip_runtime.h>
#include <stdint.h>

#define D_  1024
#define S_  2048
#define B_  2
#define H_  16
#define HD_ 64
#define M_  (B_*S_)   // 4096
#define KVB 64

typedef unsigned short u16;
typedef __attribute__((ext_vector_type(8)))  __bf16 bf16x8;
typedef __attribute__((ext_vector_type(4)))  float  f32x4;
typedef __attribute__((ext_vector_type(16))) float  f32x16;

__device__ __forceinline__ u16 f2bf(float f) {
    __bf16 h = (__bf16)f;
    union { __bf16 h; u16 u; } x; x.h = h;
    return x.u;
}

// 2^x via the raw transcendental (1 instr). __builtin_exp2f lowers to the
// OCML precise path (~6 instrs, +13pts VALUBusy measured R7) — do NOT use it.
__device__ __forceinline__ float exp2_fast(float x) {
    float r;
    asm("v_exp_f32 %0, %1" : "=v"(r) : "v"(x));
    return r;
}

__device__ __forceinline__ void gload_lds16(const void* g, void* l) {
    __builtin_amdgcn_global_load_lds(
        (const __attribute__((address_space(1))) uint32_t*)g,
        (__attribute__((address_space(3))) uint32_t*)l, 16, 0, 0);
}

// ---------------- prep: fp32->bf16 cvt (x3) + W transpose (x3), one launch --
__global__ __launch_bounds__(256) void prep_kernel(
    const float* __restrict__ q, const float* __restrict__ k, const float* __restrict__ v,
    u16* __restrict__ Xq, u16* __restrict__ Xk, u16* __restrict__ Xv,
    const float* __restrict__ Wq, const float* __restrict__ Wk, const float* __restrict__ Wv,
    u16* __restrict__ Wtq, u16* __restrict__ Wtk, u16* __restrict__ Wtv)
{
    __shared__ u16 t[64][65];
    int bid = blockIdx.x;
    if (bid < 12288) {                       // cvt: 3 x 4096 blocks
        int sl = bid >> 12;
        int bx = bid & 4095;
        const float* in = sl == 0 ? q : (sl == 1 ? k : v);
        u16* out = sl == 0 ? Xq : (sl == 1 ? Xk : Xv);
        int i = (bx * 256 + threadIdx.x) * 4;
        float4 vv = *(const float4*)(in + i);
        ushort4 o;
        o.x = f2bf(vv.x); o.y = f2bf(vv.y); o.z = f2bf(vv.z); o.w = f2bf(vv.w);
        *(ushort4*)(out + i) = o;
    } else {                                 // transpose: 3 x 256 blocks
        int tt = bid - 12288;
        int z = tt >> 8;
        int rem = tt & 255;
        const float* W = z == 0 ? Wq : (z == 1 ? Wk : Wv);
        u16* Wt = z == 0 ? Wtq : (z == 1 ? Wtk : Wtv);
        int k0 = (rem & 15) * 64, n0 = (rem >> 4) * 64;
        int tid = threadIdx.x;
        int c4 = (tid & 15) * 4, r = tid >> 4;
#pragma unroll
        for (int i = 0; i < 4; i++) {
            int row = r + i * 16;
            float4 vv = *(const float4*)(W + (uint64_t)(k0 + row) * D_ + n0 + c4);
            t[row][c4 + 0] = f2bf(vv.x);
            t[row][c4 + 1] = f2bf(vv.y);
            t[row][c4 + 2] = f2bf(vv.z);
            t[row][c4 + 3] = f2bf(vv.w);
        }
        __syncthreads();
#pragma unroll
        for (int i = 0; i < 4; i++) {
            int nrow = r + i * 16;
            ushort4 o;
            o.x = t[c4 + 0][nrow]; o.y = t[c4 + 1][nrow];
            o.z = t[c4 + 2][nrow]; o.w = t[c4 + 3][nrow];
            *(ushort4*)(Wt + (uint64_t)(n0 + nrow) * D_ + k0 + c4) = o;
        }
    }
}

// ---------------- QKV projection GEMM: 64x128 tile, BK=32 ------------------
// 4 waves, each wave a 32x64 quadrant -> acc[2][4] = 32 AGPR.
// Depth-2 pipeline: 3 LDS buffers, raw s_barrier + counted vmcnt(3).
// LDS chunk-swizzle (c ^= (row>>1)&3) keeps ds_read_b128 conflict-free.
__global__ __launch_bounds__(256) void gemm_qkv(
    const u16* __restrict__ Xq, const u16* __restrict__ Xk, const u16* __restrict__ Xv,
    const u16* __restrict__ Wtq, const u16* __restrict__ Wtk, const u16* __restrict__ Wtv,
    const float* __restrict__ bq, const float* __restrict__ bk, const float* __restrict__ bv,
    u16* __restrict__ Qo, u16* __restrict__ Ko, u16* __restrict__ Vo)
{
    int p = blockIdx.z;
    const u16* X    = p == 0 ? Xq  : (p == 1 ? Xk  : Xv);
    const u16* Wt   = p == 0 ? Wtq : (p == 1 ? Wtk : Wtv);
    const float* bias = p == 0 ? bq : (p == 1 ? bk : bv);
    u16* out = p == 0 ? Qo : (p == 1 ? Ko : Vo);
    // Q: fold 1/sqrt(HD) AND log2(e) -> softmax runs in exp2 domain
    float scale = p == 0 ? 0.18033688f : 1.0f;

    __shared__ __align__(16) u16 As[3][64 * 32];    // 12 KB
    __shared__ __align__(16) u16 Bs[3][128 * 32];   // 24 KB

    int tid = threadIdx.x;
    int lane = tid & 63, wid = tid >> 6;
    int lrow = lane & 15, lk = lane >> 4;
    int wr = wid >> 1, wc = wid & 1;
    int bm = blockIdx.x, bn = blockIdx.y;

    f32x4 acc[2][4] = {};

    const uint64_t Xrow0 = (uint64_t)bm * 64 * D_;
    const uint64_t Wrow0 = (uint64_t)bn * 128 * D_;

    auto stage = [&](int buf, int kt) {
        int k0 = kt * 32;
        {
            int row = tid >> 2;
            int cg = (tid & 3) ^ ((row >> 1) & 3);
            gload_lds16(X + Xrow0 + (uint64_t)row * D_ + k0 + cg * 8,
                        (char*)As[buf] + wid * 1024);
        }
#pragma unroll
        for (int it = 0; it < 2; ++it) {
            int i = it * 256 + tid;
            int row = i >> 2;
            int cg = (i & 3) ^ ((row >> 1) & 3);
            gload_lds16(Wt + Wrow0 + (uint64_t)row * D_ + k0 + cg * 8,
                        (char*)Bs[buf] + it * 4096 + wid * 1024);
        }
    };

    stage(0, 0);
    stage(1, 1);
    asm volatile("s_waitcnt vmcnt(3)" ::: "memory");
    __builtin_amdgcn_s_barrier();

    const int NKT = D_ / 32;   // 32
    for (int kt = 0; kt < NKT; ++kt) {
        int cur = kt % 3;
        if (kt + 2 < NKT) stage((kt + 2) % 3, kt + 2);

        bf16x8 a[2], b[4];
#pragma unroll
        for (int m = 0; m < 2; m++) {
            int r = wr * 32 + m * 16 + lrow;
            a[m] = *(const bf16x8*)((const char*)As[cur] + r * 64 + ((lk ^ ((r >> 1) & 3)) * 16));
        }
#pragma unroll
        for (int n = 0; n < 4; n++) {
            int r = wc * 64 + n * 16 + lrow;
            b[n] = *(const bf16x8*)((const char*)Bs[cur] + r * 64 + ((lk ^ ((r >> 1) & 3)) * 16));
        }
        if (p < 2) {
#pragma unroll
            for (int m = 0; m < 2; m++)
#pragma unroll
                for (int n = 0; n < 4; n++)
                    acc[m][n] = __builtin_amdgcn_mfma_f32_16x16x32_bf16(a[m], b[n], acc[m][n], 0, 0, 0);
        } else {  // V: compute C^T so VT stores coalesce
#pragma unroll
            for (int m = 0; m < 2; m++)
#pragma unroll
                for (int n = 0; n < 4; n++)
                    acc[m][n] = __builtin_amdgcn_mfma_f32_16x16x32_bf16(b[n], a[m], acc[m][n], 0, 0, 0);
        }

        if (kt + 1 < NKT) {
            if (kt + 2 < NKT)
                asm volatile("s_waitcnt vmcnt(3)" ::: "memory");
            else
                asm volatile("s_waitcnt vmcnt(0)" ::: "memory");
            __builtin_amdgcn_s_barrier();
        }
    }

    if (p < 2) {
#pragma unroll
        for (int m = 0; m < 2; m++) {
            int grow_base = bm * 64 + wr * 32 + m * 16 + lk * 4;
#pragma unroll
            for (int n = 0; n < 4; n++) {
                int gcol = bn * 128 + wc * 64 + n * 16 + lrow;
                float bb = bias[gcol];
                int h = gcol >> 6, hd = gcol & 63;
#pragma unroll
                for (int j = 0; j < 4; j++) {
                    int grow = grow_base + j;
                    int b_ = grow >> 11, s = grow & 2047;
                    out[(((uint64_t)(b_ * H_ + h)) * S_ + s) * HD_ + hd] =
                        f2bf((acc[m][n][j] + bb) * scale);
                }
            }
        }
    } else {
#pragma unroll
        for (int m = 0; m < 2; m++) {
            int sg = bm * 64 + wr * 32 + m * 16 + lrow;
            int b_ = sg >> 11, s = sg & 2047;
#pragma unroll
            for (int n = 0; n < 4; n++) {
                int ch_base = bn * 128 + wc * 64 + n * 16 + lk * 4;
#pragma unroll
                for (int j = 0; j < 4; j++) {
                    int ch = ch_base + j;
                    int h = ch >> 6, hd = ch & 63;
                    out[(((uint64_t)(b_ * H_ + h)) * HD_ + hd) * S_ + s] =
                        f2bf(acc[m][n][j] + bias[ch]);
                }
            }
        }
    }
}

// ---------------- flash attention: 8 waves x 32 q-rows (QBLK=256), KVBLK=64 -
// Swapped QK^T (mfma(K,Q)): lane holds P-row slice for q=lane&31 -> in-reg
// softmax in exp2 domain (log2e folded into Q): tree max (ILP), defer-max
// rescale skip (T13, THR=8), tree sum, asm v_exp_f32 (1 instr),
// cvt_pk+permlane32 P redistribution (T12). PV swapped -> D[hd][q].
__global__ __launch_bounds__(512) void attn_kernel(
    const u16* __restrict__ Q, const u16* __restrict__ K,
    const u16* __restrict__ VT, float* __restrict__ out)
{
    __shared__ __align__(16) char smem[32768];  // K dbuf 16K | V dbuf 16K; scr overlays

    int lin = blockIdx.x;
    int bh = lin & 31, qt = lin >> 5;

    int tid = threadIdx.x;
    int w = tid >> 6, lane = tid & 63;
    int q5 = lane & 31, h = lane >> 5;

    bf16x8 qf[4];
    const u16* Qrow = Q + ((uint64_t)bh * S_ + qt * 256 + w * 32 + q5) * HD_;
#pragma unroll
    for (int kk = 0; kk < 4; kk++)
        qf[kk] = *(const bf16x8*)(Qrow + kk * 16 + h * 8);

    f32x16 o_acc[2] = {};
    float m_run = -1e30f, l_run = 0.f;

    const char* Kbase = (const char*)(K  + (uint64_t)bh * S_ * HD_);
    const char* Vbase = (const char*)(VT + (uint64_t)bh * HD_ * S_);

    int o16 = tid * 16;
    int rr  = o16 >> 7;
    int os  = o16 ^ ((rr & 7) << 4);

    auto stage = [&](int buf, int t) {
        int kv0 = t * KVB;
        gload_lds16(Kbase + (uint64_t)kv0 * 128 + os,
                    smem + buf * 8192 + w * 1024);
        gload_lds16(Vbase + (uint64_t)rr * (S_ * 2) + kv0 * 2 + (os & 127),
                    smem + 16384 + buf * 8192 + w * 1024);
    };

    stage(0, 0);
    __syncthreads();
    int cur = 0;

    const int NT = S_ / KVB;
    for (int t = 0; t < NT; ++t) {
        if (t + 1 < NT) stage(cur ^ 1, t + 1);

        const char* Kc = smem + cur * 8192;
        const char* Vc = smem + 16384 + cur * 8192;
        int sw = (q5 & 7) << 4;

        // ---- S^T = K Q^T (scores already in log2 units) ----
        f32x16 sacc[2] = {};
        __builtin_amdgcn_s_setprio(1);
#pragma unroll
        for (int c = 0; c < 2; c++) {
            int rb = (c * 32 + q5) * 128;
#pragma unroll
            for (int kk = 0; kk < 4; kk++) {
                bf16x8 kf = *(const bf16x8*)(Kc + rb + ((kk * 32 + h * 16) ^ sw));
                sacc[c] = __builtin_amdgcn_mfma_f32_32x32x16_bf16(kf, qf[kk], sacc[c], 0, 0, 0);
            }
        }
        __builtin_amdgcn_s_setprio(0);

        // ---- row max: depth-5 tree (ILP) + cross-half swap ----
        float tm[16];
#pragma unroll
        for (int r = 0; r < 16; r++) tm[r] = fmaxf(sacc[0][r], sacc[1][r]);
#pragma unroll
        for (int s2 = 8; s2 > 0; s2 >>= 1)
#pragma unroll
            for (int r = 0; r < s2; r++) tm[r] = fmaxf(tm[r], tm[r + s2]);
        float pmax = fmaxf(tm[0], __shfl_xor(tm[0], 32, 64));

        // ---- defer-max (T13): skip O/l rescale while growth <= 8 (P<=256) --
        if (!__all(pmax - m_run <= 8.0f)) {
            float mnew = fmaxf(m_run, pmax);
            float sc = exp2_fast(m_run - mnew);
            m_run = mnew;
            l_run *= sc;
#pragma unroll
            for (int hb = 0; hb < 2; hb++)
#pragma unroll
                for (int r = 0; r < 16; r++) o_acc[hb][r] *= sc;
        }

        // ---- P = exp2(s - m), 4-way parallel sum accumulators ----
        float ts0 = 0.f, ts1 = 0.f, ts2 = 0.f, ts3 = 0.f;
#pragma unroll
        for (int c = 0; c < 2; c++)
#pragma unroll
            for (int r = 0; r < 16; r += 4) {
                float p0 = exp2_fast(sacc[c][r + 0] - m_run);
                float p1 = exp2_fast(sacc[c][r + 1] - m_run);
                float p2 = exp2_fast(sacc[c][r + 2] - m_run);
                float p3 = exp2_fast(sacc[c][r + 3] - m_run);
                sacc[c][r + 0] = p0; sacc[c][r + 1] = p1;
                sacc[c][r + 2] = p2; sacc[c][r + 3] = p3;
                ts0 += p0; ts1 += p1; ts2 += p2; ts3 += p3;
            }
        float ts = (ts0 + ts1) + (ts2 + ts3);
        ts += __shfl_xor(ts, 32, 64);
        l_run += ts;

        // ---- P -> PV B-operand: cvt_pk pairs + permlane32_swap (T12) ----
        bf16x8 pa[4];
#pragma unroll
        for (int ks = 0; ks < 4; ks++) {
            int c = ks >> 1, gg = ks & 1;
            uint32_t a0, a1, b0, b1;
            asm("v_cvt_pk_bf16_f32 %0, %1, %2" : "=v"(a0) : "v"(sacc[c][8*gg+0]), "v"(sacc[c][8*gg+1]));
            asm("v_cvt_pk_bf16_f32 %0, %1, %2" : "=v"(a1) : "v"(sacc[c][8*gg+2]), "v"(sacc[c][8*gg+3]));
            asm("v_cvt_pk_bf16_f32 %0, %1, %2" : "=v"(b0) : "v"(sacc[c][8*gg+4]), "v"(sacc[c][8*gg+5]));
            asm("v_cvt_pk_bf16_f32 %0, %1, %2" : "=v"(b1) : "v"(sacc[c][8*gg+6]), "v"(sacc[c][8*gg+7]));
            asm volatile("v_permlane32_swap_b32 %0, %1" : "+v"(a0), "+v"(b0));
            asm volatile("v_permlane32_swap_b32 %0, %1" : "+v"(a1), "+v"(b1));
            union { uint32_t u[4]; bf16x8 v; } pu;
            pu.u[0] = a0; pu.u[1] = a1; pu.u[2] = b0; pu.u[3] = b1;
            pa[ks] = pu.v;
        }

        // ---- O^T += V^T P^T ----
        __builtin_amdgcn_s_setprio(1);
#pragma unroll
        for (int hb = 0; hb < 2; hb++) {
            int rb = (hb * 32 + q5) * 128;
#pragma unroll
            for (int ks = 0; ks < 4; ks++) {
                bf16x8 vf = *(const bf16x8*)(Vc + rb + ((ks * 32 + h * 16) ^ sw));
                o_acc[hb] = __builtin_amdgcn_mfma_f32_32x32x16_bf16(vf, pa[ks], o_acc[hb], 0, 0, 0);
            }
        }
        __builtin_amdgcn_s_setprio(0);

        __syncthreads();
        cur ^= 1;
    }

    // ---- epilogue: per-wave 32x32 f32 LDS transpose (overlays K/V bufs) ----
    float inv = 1.0f / l_run;
    int b_ = bh >> 4, head = bh & 15;
    int qq = lane >> 1, c0 = (lane & 1) * 16;
    float* scrw = (float*)smem + w * 1024;
    float* orow = out + ((uint64_t)(b_ * S_ + qt * 256 + w * 32 + qq)) * D_ + head * 64;
#pragma unroll
    for (int hb = 0; hb < 2; hb++) {
#pragma unroll
        for (int r = 0; r < 16; r++) {
            int col = (r & 3) + 8 * (r >> 2) + 4 * h;
            scrw[q5 * 32 + (col ^ ((q5 & 7) << 2))] = o_acc[hb][r] * inv;
        }
        __syncthreads();
#pragma unroll
        for (int j = 0; j < 4; j++) {
            int cb = c0 + j * 4;
            float4 val = *(float4*)&scrw[qq * 32 + (cb ^ ((qq & 7) << 2))];
            *(float4*)(orow + hb * 32 + cb) = val;
        }
        __syncthreads();
    }
}

// ---------------- launcher ----------------
extern "C" void kernel_launch(void* const* d_in, const int* in_sizes, int n_in,
                              void* d_out, int out_size, void* d_ws, size_t ws_size,
                              hipStream_t stream) {
    const float* q  = (const float*)d_in[0];
    const float* k  = (const float*)d_in[1];
    const float* v  = (const float*)d_in[2];
    const float* Wq = (const float*)d_in[3];
    const float* bq = (const float*)d_in[4];
    const float* Wk = (const float*)d_in[5];
    const float* bk = (const float*)d_in[6];
    const float* Wv = (const float*)d_in[7];
    const float* bv = (const float*)d_in[8];
    float* out = (float*)d_out;

    u16* ws = (u16*)d_ws;
    const size_t XN = (size_t)M_ * D_;   // 4 Mi elems
    const size_t WN = (size_t)D_ * D_;   // 1 Mi elems
    u16* Xq  = ws;          u16* Xk  = Xq  + XN;  u16* Xv  = Xk  + XN;
    u16* Wtq = Xv + XN;     u16* Wtk = Wtq + WN;  u16* Wtv = Wtk + WN;
    u16* Qb  = Wtv + WN;    u16* Kb  = Qb  + XN;  u16* Vb  = Kb  + XN;

    prep_kernel<<<13056, 256, 0, stream>>>(q, k, v, Xq, Xk, Xv,
                                           Wq, Wk, Wv, Wtq, Wtk, Wtv);
    gemm_qkv<<<dim3(64, 8, 3), 256, 0, stream>>>(Xq, Xk, Xv, Wtq, Wtk, Wtv,
                                                 bq, bk, bv, Qb, Kb, Vb);
    attn_kernel<<<256, 512, 0, stream>>>(Qb, Kb, Vb, out);
}